// Round 8
// baseline (1007.197 us; speedup 1.0000x reference)
//
#include <hip/hip_runtime.h>
#include <stdint.h>

typedef _Float16 f16x8 __attribute__((ext_vector_type(8)));
typedef float f32x4 __attribute__((ext_vector_type(4)));

__device__ __forceinline__ float sigf(float x) {
    return __builtin_amdgcn_rcpf(1.0f + __expf(-x));
}
__device__ __forceinline__ float tanhf_fast(float x) {
    return 1.0f - 2.0f * __builtin_amdgcn_rcpf(1.0f + __expf(2.0f * x));
}

// Fused 2-layer LSTM encoder via MFMA, 16 samples/block, 1 barrier/step.
// grid = 64 blocks, block = 512 (8 waves). Waves 0-3: layer-1 step t;
// waves 4-7: layer-2 step t-1 (pipeline). All 16 MFMA N-columns = real samples.
// mfma_f32_16x16x32_f16, K=96 (L1: [Whh1 | Wih1-x | 0]) / K=128 (L2: [Wih2|Whh2]).
// VERIFIED (R7 passed): A/B share (lane,i)->k map (cancels); C/D col=lane&15,
// row=(lane>>4)*4+reg. => lane (rl,hi) holds ALL 4 gates of units
// w*16+hi*4+{0..3}, sample rl -> LSTM update fully in-register, h written
// back as one 8B ds_write_b64. No preX transpose, no second barrier.
__global__ __launch_bounds__(512, 1)
void lstm_mfma16(const float* __restrict__ x,
                 const float* __restrict__ W1i, const float* __restrict__ W1h,
                 const float* __restrict__ b1i, const float* __restrict__ b1h,
                 const float* __restrict__ W2i, const float* __restrict__ W2h,
                 const float* __restrict__ b2i, const float* __restrict__ b2h,
                 const float* __restrict__ eW,  const float* __restrict__ eb,
                 const float* __restrict__ D1i, const float* __restrict__ D1bi,
                 const float* __restrict__ D1bh,
                 const float* __restrict__ D2i, const float* __restrict__ D2bi,
                 const float* __restrict__ D2bh,
                 const float* __restrict__ dW,  const float* __restrict__ db,
                 float* __restrict__ out)
{
    // [buf][col(sample)][k]; col stride 104 f16 = 208 B (16B-aligned).
    // h1b k: 0..63 h1, 64..66 x(t), 67..95 zero (K=96), 96..103 pad.
    __shared__ __align__(16) _Float16 h1b[2][16][104];
    // h2b k: 0..63 h2, 64..71 pad (stride 144 B, 16B-aligned).
    __shared__ __align__(16) _Float16 h2b[2][16][72];
    __shared__ float uW[8][8];      // per-wave tail scratch
    __shared__ float tlA[8][64];
    __shared__ float tlB[8][64];

    const int tid = threadIdx.x, blk = blockIdx.x;
    const int wid = tid >> 6, lane = tid & 63;
    const int rl = lane & 15, hi = lane >> 4;
    const bool isL1 = (wid < 4);
    const int w = isL1 ? wid : wid - 4;   // unit-group: units [16w, 16w+16)

    // ---- zero h buffers (pads must stay 0 forever) ----
    {
        uint32_t* z1 = (uint32_t*)&h1b[0][0][0];
        for (int i = tid; i < 1664; i += 512) z1[i] = 0u;   // 2*16*104/2
        uint32_t* z2 = (uint32_t*)&h2b[0][0][0];
        for (int i = tid; i < 1152; i += 512) z2[i] = 0u;   // 2*16*72/2
    }

    // ---- pack A-frags (weights, f16) into registers/AGPRs ----
    // A map: row = rl, k = s*32 + hi*8 + i  (same map used for B reads).
    f16x8 afr[4][4];
    #pragma unroll
    for (int g = 0; g < 4; ++g) {
        const int grow = g * 64 + w * 16 + rl;  // global gate-row
        if (isL1) {
            #pragma unroll
            for (int s = 0; s < 2; ++s) {
                f16x8 v;
                #pragma unroll
                for (int i = 0; i < 8; ++i)
                    v[i] = (_Float16)W1h[grow * 64 + s * 32 + hi * 8 + i];
                afr[g][s] = v;
            }
            {
                f16x8 v;
                #pragma unroll
                for (int i = 0; i < 8; ++i) {
                    int kk = hi * 8 + i;
                    v[i] = (kk < 3) ? (_Float16)W1i[grow * 3 + kk] : (_Float16)0.0f;
                }
                afr[g][2] = v;
            }
            {
                f16x8 v;
                #pragma unroll
                for (int i = 0; i < 8; ++i) v[i] = (_Float16)0.0f;
                afr[g][3] = v;
            }
        } else {
            #pragma unroll
            for (int s = 0; s < 2; ++s) {
                f16x8 v;
                #pragma unroll
                for (int i = 0; i < 8; ++i)
                    v[i] = (_Float16)W2i[grow * 64 + s * 32 + hi * 8 + i];
                afr[g][s] = v;
            }
            #pragma unroll
            for (int s = 0; s < 2; ++s) {
                f16x8 v;
                #pragma unroll
                for (int i = 0; i < 8; ++i)
                    v[i] = (_Float16)W2h[grow * 64 + s * 32 + hi * 8 + i];
                afr[g][2 + s] = v;
            }
        }
    }

    // ---- biases folded into acc init; C/D row = hi*4 + r ----
    f32x4 bias[4];
    #pragma unroll
    for (int g = 0; g < 4; ++g) {
        #pragma unroll
        for (int r = 0; r < 4; ++r) {
            int grow = g * 64 + w * 16 + hi * 4 + r;
            bias[g][r] = isL1 ? (b1i[grow] + b1h[grow]) : (b2i[grow] + b2h[grow]);
        }
    }

    // c-state: lane (rl,hi) owns units w*16+hi*4+{0..3}, sample rl.
    float cst[4] = {0.0f, 0.0f, 0.0f, 0.0f};

    __syncthreads();
    // prestage x(0) into buf 0 (16 samples)
    if (wid == 0 && lane < 16) {
        const float* xp = x + (size_t)(blk * 16 + lane) * 3072;
        h1b[0][lane][64] = (_Float16)xp[0];
        h1b[0][lane][65] = (_Float16)xp[1];
        h1b[0][lane][66] = (_Float16)xp[2];
    }
    __syncthreads();

    #pragma unroll 1
    for (int t = 0; t <= 1024; ++t) {
        const int p = t & 1;   // read h1(t-1)/h2(t-2) from [p], write to [p^1]

        // x(t+1) prefetch into registers (issued early, consumed pre-barrier)
        float xf0 = 0.f, xf1 = 0.f, xf2 = 0.f;
        const bool doX = (wid == 0) && (lane < 16) && (t + 1 < 1024);
        if (doX) {
            const float* xp = x + (size_t)(blk * 16 + lane) * 3072 + (size_t)(t + 1) * 3;
            xf0 = xp[0]; xf1 = xp[1]; xf2 = xp[2];
        }

        if (isL1 && t < 1024) {
            f32x4 a0 = bias[0], a1 = bias[1], a2 = bias[2], a3 = bias[3];
            #pragma unroll
            for (int s = 0; s < 3; ++s) {
                f16x8 bf = *(const f16x8*)&h1b[p][rl][s * 32 + hi * 8];
                a0 = __builtin_amdgcn_mfma_f32_16x16x32_f16(afr[0][s], bf, a0, 0, 0, 0);
                a1 = __builtin_amdgcn_mfma_f32_16x16x32_f16(afr[1][s], bf, a1, 0, 0, 0);
                a2 = __builtin_amdgcn_mfma_f32_16x16x32_f16(afr[2][s], bf, a2, 0, 0, 0);
                a3 = __builtin_amdgcn_mfma_f32_16x16x32_f16(afr[3][s], bf, a3, 0, 0, 0);
            }
            // in-register update: 4 (unit,sample) states per lane
            uint16_t hu[4];
            #pragma unroll
            for (int r = 0; r < 4; ++r) {
                float pi = a0[r], pf = a1[r], pgg = a2[r], po = a3[r];
                cst[r] = sigf(pf) * cst[r] + sigf(pi) * tanhf_fast(pgg);
                float hn = sigf(po) * tanhf_fast(cst[r]);
                hu[r] = __builtin_bit_cast(uint16_t, (_Float16)hn);
            }
            uint2 pk;
            pk.x = (uint32_t)hu[0] | ((uint32_t)hu[1] << 16);
            pk.y = (uint32_t)hu[2] | ((uint32_t)hu[3] << 16);
            *(uint2*)&h1b[p ^ 1][rl][w * 16 + hi * 4] = pk;   // 8B ds_write_b64
        } else if (!isL1 && t >= 1) {
            f32x4 a0 = bias[0], a1 = bias[1], a2 = bias[2], a3 = bias[3];
            #pragma unroll
            for (int s = 0; s < 2; ++s) {   // Wih2 · h1(t-1)
                f16x8 bf = *(const f16x8*)&h1b[p][rl][s * 32 + hi * 8];
                a0 = __builtin_amdgcn_mfma_f32_16x16x32_f16(afr[0][s], bf, a0, 0, 0, 0);
                a1 = __builtin_amdgcn_mfma_f32_16x16x32_f16(afr[1][s], bf, a1, 0, 0, 0);
                a2 = __builtin_amdgcn_mfma_f32_16x16x32_f16(afr[2][s], bf, a2, 0, 0, 0);
                a3 = __builtin_amdgcn_mfma_f32_16x16x32_f16(afr[3][s], bf, a3, 0, 0, 0);
            }
            #pragma unroll
            for (int s = 0; s < 2; ++s) {   // Whh2 · h2(t-2)
                f16x8 bf = *(const f16x8*)&h2b[p][rl][s * 32 + hi * 8];
                a0 = __builtin_amdgcn_mfma_f32_16x16x32_f16(afr[0][2 + s], bf, a0, 0, 0, 0);
                a1 = __builtin_amdgcn_mfma_f32_16x16x32_f16(afr[1][2 + s], bf, a1, 0, 0, 0);
                a2 = __builtin_amdgcn_mfma_f32_16x16x32_f16(afr[2][2 + s], bf, a2, 0, 0, 0);
                a3 = __builtin_amdgcn_mfma_f32_16x16x32_f16(afr[3][2 + s], bf, a3, 0, 0, 0);
            }
            uint16_t hu[4];
            #pragma unroll
            for (int r = 0; r < 4; ++r) {
                float pi = a0[r], pf = a1[r], pgg = a2[r], po = a3[r];
                cst[r] = sigf(pf) * cst[r] + sigf(pi) * tanhf_fast(pgg);
                float hn = sigf(po) * tanhf_fast(cst[r]);
                hu[r] = __builtin_bit_cast(uint16_t, (_Float16)hn);
            }
            uint2 pk;
            pk.x = (uint32_t)hu[0] | ((uint32_t)hu[1] << 16);
            pk.y = (uint32_t)hu[2] | ((uint32_t)hu[3] << 16);
            *(uint2*)&h2b[p ^ 1][rl][w * 16 + hi * 4] = pk;
        }

        // stage x(t+1) for next iteration's L1 read
        if (doX) {
            h1b[p ^ 1][lane][64] = (_Float16)xf0;
            h1b[p ^ 1][lane][65] = (_Float16)xf1;
            h1b[p ^ 1][lane][66] = (_Float16)xf2;
        }
        __syncthreads();
        // hazards: all reads hit buf [p], all writes hit buf [p^1]; swap at barrier.
    }
    // final h2(1023) was written at t=1024 (p=0) into h2b[1].

    // ---- decoder tail: wave wid handles samples {2wid, 2wid+1} ----
    #pragma unroll 1
    for (int ss = 0; ss < 2; ++ss) {
        const int s = wid * 2 + ss;
        const int S = blk * 16 + s;

        if (lane < 5) {   // u = enc_fc(h2_final)
            float acc = eb[lane];
            for (int k = 0; k < 64; ++k)
                acc += eW[lane * 64 + k] * (float)h2b[1][s][k];
            uW[wid][lane] = acc;
            out[S * 5 + lane] = acc;
        }
        __syncthreads();

        {   // d1: single step from zero state (only i, g, o gates matter)
            float u0 = uW[wid][0], u1 = uW[wid][1], u2 = uW[wid][2],
                  u3 = uW[wid][3], u4 = uW[wid][4];
            int ri = lane, rg = 128 + lane, ro = 192 + lane;
            float pi = D1bi[ri] + D1bh[ri];
            float pg = D1bi[rg] + D1bh[rg];
            float po = D1bi[ro] + D1bh[ro];
            pi += D1i[ri*5+0]*u0 + D1i[ri*5+1]*u1 + D1i[ri*5+2]*u2 + D1i[ri*5+3]*u3 + D1i[ri*5+4]*u4;
            pg += D1i[rg*5+0]*u0 + D1i[rg*5+1]*u1 + D1i[rg*5+2]*u2 + D1i[rg*5+3]*u3 + D1i[rg*5+4]*u4;
            po += D1i[ro*5+0]*u0 + D1i[ro*5+1]*u1 + D1i[ro*5+2]*u2 + D1i[ro*5+3]*u3 + D1i[ro*5+4]*u4;
            float cd = sigf(pi) * tanhf_fast(pg);
            float hd = sigf(po) * tanhf_fast(cd);
            tlA[wid][lane] = hd;
        }
        __syncthreads();

        {   // d2: single step from zero state
            int ri = lane, rg = 128 + lane, ro = 192 + lane;
            float pi = D2bi[ri] + D2bh[ri];
            float pg = D2bi[rg] + D2bh[rg];
            float po = D2bi[ro] + D2bh[ro];
            for (int k = 0; k < 64; ++k) {
                float hk = tlA[wid][k];
                pi += D2i[ri * 64 + k] * hk;
                pg += D2i[rg * 64 + k] * hk;
                po += D2i[ro * 64 + k] * hk;
            }
            float cd = sigf(pi) * tanhf_fast(pg);
            float hd = sigf(po) * tanhf_fast(cd);
            tlB[wid][lane] = hd;
        }
        __syncthreads();

        if (lane < 3) {   // tau = dec_fc(h_d2)
            float acc = db[lane];
            for (int k = 0; k < 64; ++k) acc += dW[lane * 64 + k] * tlB[wid][k];
            out[5120 + S * 3 + lane] = acc;
        }
        __syncthreads();
    }
}

extern "C" void kernel_launch(void* const* d_in, const int* in_sizes, int n_in,
                              void* d_out, int out_size, void* d_ws, size_t ws_size,
                              hipStream_t stream) {
    (void)in_sizes; (void)n_in; (void)out_size; (void)d_ws; (void)ws_size;
    const float* x    = (const float*)d_in[0];
    const float* W1i  = (const float*)d_in[1];
    const float* W1h  = (const float*)d_in[2];
    const float* b1i  = (const float*)d_in[3];
    const float* b1h  = (const float*)d_in[4];
    const float* W2i  = (const float*)d_in[5];
    const float* W2h  = (const float*)d_in[6];
    const float* b2i  = (const float*)d_in[7];
    const float* b2h  = (const float*)d_in[8];
    const float* eW   = (const float*)d_in[9];
    const float* eb   = (const float*)d_in[10];
    const float* D1i  = (const float*)d_in[11];
    const float* D1bi = (const float*)d_in[13];
    const float* D1bh = (const float*)d_in[14];
    const float* D2i  = (const float*)d_in[15];
    const float* D2bi = (const float*)d_in[17];
    const float* D2bh = (const float*)d_in[18];
    const float* dW   = (const float*)d_in[19];
    const float* db   = (const float*)d_in[20];

    hipLaunchKernelGGL(lstm_mfma16, dim3(64), dim3(512), 0, stream,
                       x, W1i, W1h, b1i, b1h, W2i, W2h, b2i, b2h, eW, eb,
                       D1i, D1bi, D1bh, D2i, D2bi, D2bh, dW, db,
                       (float*)d_out);
}

// Round 10
// 984.008 us; speedup vs baseline: 1.0236x; 1.0236x over previous
//
#include <hip/hip_runtime.h>
#include <stdint.h>

typedef _Float16 f16x8 __attribute__((ext_vector_type(8)));
typedef float f32x4 __attribute__((ext_vector_type(4)));

__device__ __forceinline__ float sigf(float x) {
    return __builtin_amdgcn_rcpf(1.0f + __expf(-x));
}
__device__ __forceinline__ float tanhf_fast(float x) {
    return 1.0f - 2.0f * __builtin_amdgcn_rcpf(1.0f + __expf(2.0f * x));
}
__device__ __forceinline__ uint32_t pk2f(float a, float b) {
    uint16_t ua = __builtin_bit_cast(uint16_t, (_Float16)a);
    uint16_t ub = __builtin_bit_cast(uint16_t, (_Float16)b);
    return (uint32_t)ua | ((uint32_t)ub << 16);
}

// Fused 2-layer LSTM encoder via MFMA, 16 samples/block, 1 barrier/step,
// 16-step-deep x prefetch. R9 NaN root cause: xs slots 4..7 were never
// initialized but fed the 16B B-frag read (0 x NaN = NaN in MFMA). Fix:
// zero-fill ALL of xs at startup; writes only touch slots 0..3 thereafter.
// grid = 64 blocks, block = 512 (8 waves). Waves 0-3: layer-1 step t;
// waves 4-7: layer-2 step t-1 (pipeline).
// mfma_f32_16x16x32_f16. L1: K=96 = [Whh1 | Wih1&x | 0]; x slice from xs
// chunk buffer (hi==0 lanes only; A zero for k>=3). L2: K=128 = [Wih2|Whh2].
// VERIFIED (R7/R8): A/B share (lane,i)->k map; C/D col=lane&15,
// row=(lane>>4)*4+reg -> in-register LSTM update, h written as 8B ds_write.
__global__ __launch_bounds__(512, 1)
void lstm_mfma16(const float* __restrict__ x,
                 const float* __restrict__ W1i, const float* __restrict__ W1h,
                 const float* __restrict__ b1i, const float* __restrict__ b1h,
                 const float* __restrict__ W2i, const float* __restrict__ W2h,
                 const float* __restrict__ b2i, const float* __restrict__ b2h,
                 const float* __restrict__ eW,  const float* __restrict__ eb,
                 const float* __restrict__ D1i, const float* __restrict__ D1bi,
                 const float* __restrict__ D1bh,
                 const float* __restrict__ D2i, const float* __restrict__ D2bi,
                 const float* __restrict__ D2bh,
                 const float* __restrict__ dW,  const float* __restrict__ db,
                 float* __restrict__ out)
{
    // [buf][col(sample)][k]; col stride 72 f16 = 144 B (16B-aligned).
    __shared__ __align__(16) _Float16 h1b[2][16][72];
    __shared__ __align__(16) _Float16 h2b[2][16][72];
    // x chunk double buffer: [buf][t&15][sample][slot0..7] (slots 0..2 = x,
    // 3..7 permanently zero).
    __shared__ __align__(16) _Float16 xs[2][16][16][8];
    __shared__ float uW[8][8];
    __shared__ float tlA[8][64];
    __shared__ float tlB[8][64];

    const int tid = threadIdx.x, blk = blockIdx.x;
    const int wid = tid >> 6, lane = tid & 63;
    const int rl = lane & 15, hi = lane >> 4;
    const bool isL1 = (wid < 4);
    const int w = isL1 ? wid : wid - 4;   // unit-group: units [16w, 16w+16)

    // ---- zero LDS buffers (ALL bytes that ever feed an MFMA B-frag) ----
    {
        uint32_t* z1 = (uint32_t*)&h1b[0][0][0];
        for (int i = tid; i < 1152; i += 512) z1[i] = 0u;   // 2*16*72/2
        uint32_t* z2 = (uint32_t*)&h2b[0][0][0];
        for (int i = tid; i < 1152; i += 512) z2[i] = 0u;
        uint32_t* z3 = (uint32_t*)&xs[0][0][0][0];
        for (int i = tid; i < 2048; i += 512) z3[i] = 0u;   // 2*16*16*8/2
    }

    // ---- pack A-frags (weights, f16); A map: row=rl, k=s*32+hi*8+i ----
    f16x8 afr[4][4];
    #pragma unroll
    for (int g = 0; g < 4; ++g) {
        const int grow = g * 64 + w * 16 + rl;
        if (isL1) {
            #pragma unroll
            for (int s = 0; s < 2; ++s) {
                f16x8 v;
                #pragma unroll
                for (int i = 0; i < 8; ++i)
                    v[i] = (_Float16)W1h[grow * 64 + s * 32 + hi * 8 + i];
                afr[g][s] = v;
            }
            {
                f16x8 v;
                #pragma unroll
                for (int i = 0; i < 8; ++i) {
                    int kk = hi * 8 + i;
                    v[i] = (kk < 3) ? (_Float16)W1i[grow * 3 + kk] : (_Float16)0.0f;
                }
                afr[g][2] = v;
            }
            {
                f16x8 v;
                #pragma unroll
                for (int i = 0; i < 8; ++i) v[i] = (_Float16)0.0f;
                afr[g][3] = v;
            }
        } else {
            #pragma unroll
            for (int s = 0; s < 2; ++s) {
                f16x8 v;
                #pragma unroll
                for (int i = 0; i < 8; ++i)
                    v[i] = (_Float16)W2i[grow * 64 + s * 32 + hi * 8 + i];
                afr[g][s] = v;
            }
            #pragma unroll
            for (int s = 0; s < 2; ++s) {
                f16x8 v;
                #pragma unroll
                for (int i = 0; i < 8; ++i)
                    v[i] = (_Float16)W2h[grow * 64 + s * 32 + hi * 8 + i];
                afr[g][2 + s] = v;
            }
        }
    }

    // ---- biases into acc init; C/D row = hi*4 + r ----
    f32x4 bias[4];
    #pragma unroll
    for (int g = 0; g < 4; ++g) {
        #pragma unroll
        for (int r = 0; r < 4; ++r) {
            int grow = g * 64 + w * 16 + hi * 4 + r;
            bias[g][r] = isL1 ? (b1i[grow] + b1h[grow]) : (b2i[grow] + b2h[grow]);
        }
    }

    float cst[4] = {0.0f, 0.0f, 0.0f, 0.0f};

    // ---- chunk loader role: threads 0..255, (tt = tid>>4, sA = tid&15) ----
    const int tt = tid >> 4, sA = tid & 15;
    const float* xsrc = x + (size_t)(blk * 16 + sA) * 3072;
    float xr0 = 0.f, xr1 = 0.f, xr2 = 0.f;

    __syncthreads();   // zero-fill visible before any write/read

    // prologue: stage chunk 0 (t=0..15) into xs[0] (slots 0..3 only)
    if (tid < 256) {
        const float* xp = xsrc + (size_t)tt * 3;
        uint2 pk;
        pk.x = pk2f(xp[0], xp[1]);
        pk.y = pk2f(xp[2], 0.0f);
        *(uint2*)&xs[0][tt][sA][0] = pk;
    }
    __syncthreads();

    #pragma unroll 1
    for (int t = 0; t <= 1024; ++t) {
        const int p = t & 1;            // read h(t-1) from [p], write to [p^1]
        const int cb = (t >> 4) & 1;    // current x chunk buffer

        // issue next-chunk loads at chunk start (drained ~15 steps later)
        if ((t & 15) == 0 && (t + 16) < 1024 && tid < 256) {
            const float* xp = xsrc + (size_t)(t + 16 + tt) * 3;
            xr0 = xp[0]; xr1 = xp[1]; xr2 = xp[2];
        }

        if (isL1 && t < 1024) {
            f32x4 a0 = bias[0], a1 = bias[1], a2 = bias[2], a3 = bias[3];
            #pragma unroll
            for (int s = 0; s < 2; ++s) {
                f16x8 bf = *(const f16x8*)&h1b[p][rl][s * 32 + hi * 8];
                a0 = __builtin_amdgcn_mfma_f32_16x16x32_f16(afr[0][s], bf, a0, 0, 0, 0);
                a1 = __builtin_amdgcn_mfma_f32_16x16x32_f16(afr[1][s], bf, a1, 0, 0, 0);
                a2 = __builtin_amdgcn_mfma_f32_16x16x32_f16(afr[2][s], bf, a2, 0, 0, 0);
                a3 = __builtin_amdgcn_mfma_f32_16x16x32_f16(afr[3][s], bf, a3, 0, 0, 0);
            }
            {   // x slice: only hi==0 lanes carry data (A zero for k>=3)
                f16x8 bf = {};
                if (hi == 0) bf = *(const f16x8*)&xs[cb][t & 15][rl][0];
                a0 = __builtin_amdgcn_mfma_f32_16x16x32_f16(afr[0][2], bf, a0, 0, 0, 0);
                a1 = __builtin_amdgcn_mfma_f32_16x16x32_f16(afr[1][2], bf, a1, 0, 0, 0);
                a2 = __builtin_amdgcn_mfma_f32_16x16x32_f16(afr[2][2], bf, a2, 0, 0, 0);
                a3 = __builtin_amdgcn_mfma_f32_16x16x32_f16(afr[3][2], bf, a3, 0, 0, 0);
            }
            uint16_t hu[4];
            #pragma unroll
            for (int r = 0; r < 4; ++r) {
                float pi = a0[r], pf = a1[r], pgg = a2[r], po = a3[r];
                cst[r] = sigf(pf) * cst[r] + sigf(pi) * tanhf_fast(pgg);
                float hn = sigf(po) * tanhf_fast(cst[r]);
                hu[r] = __builtin_bit_cast(uint16_t, (_Float16)hn);
            }
            uint2 pk;
            pk.x = (uint32_t)hu[0] | ((uint32_t)hu[1] << 16);
            pk.y = (uint32_t)hu[2] | ((uint32_t)hu[3] << 16);
            *(uint2*)&h1b[p ^ 1][rl][w * 16 + hi * 4] = pk;
        } else if (!isL1 && t >= 1) {
            f32x4 a0 = bias[0], a1 = bias[1], a2 = bias[2], a3 = bias[3];
            #pragma unroll
            for (int s = 0; s < 2; ++s) {   // Wih2 · h1(t-1)
                f16x8 bf = *(const f16x8*)&h1b[p][rl][s * 32 + hi * 8];
                a0 = __builtin_amdgcn_mfma_f32_16x16x32_f16(afr[0][s], bf, a0, 0, 0, 0);
                a1 = __builtin_amdgcn_mfma_f32_16x16x32_f16(afr[1][s], bf, a1, 0, 0, 0);
                a2 = __builtin_amdgcn_mfma_f32_16x16x32_f16(afr[2][s], bf, a2, 0, 0, 0);
                a3 = __builtin_amdgcn_mfma_f32_16x16x32_f16(afr[3][s], bf, a3, 0, 0, 0);
            }
            #pragma unroll
            for (int s = 0; s < 2; ++s) {   // Whh2 · h2(t-2)
                f16x8 bf = *(const f16x8*)&h2b[p][rl][s * 32 + hi * 8];
                a0 = __builtin_amdgcn_mfma_f32_16x16x32_f16(afr[0][2 + s], bf, a0, 0, 0, 0);
                a1 = __builtin_amdgcn_mfma_f32_16x16x32_f16(afr[1][2 + s], bf, a1, 0, 0, 0);
                a2 = __builtin_amdgcn_mfma_f32_16x16x32_f16(afr[2][2 + s], bf, a2, 0, 0, 0);
                a3 = __builtin_amdgcn_mfma_f32_16x16x32_f16(afr[3][2 + s], bf, a3, 0, 0, 0);
            }
            uint16_t hu[4];
            #pragma unroll
            for (int r = 0; r < 4; ++r) {
                float pi = a0[r], pf = a1[r], pgg = a2[r], po = a3[r];
                cst[r] = sigf(pf) * cst[r] + sigf(pi) * tanhf_fast(pgg);
                float hn = sigf(po) * tanhf_fast(cst[r]);
                hu[r] = __builtin_bit_cast(uint16_t, (_Float16)hn);
            }
            uint2 pk;
            pk.x = (uint32_t)hu[0] | ((uint32_t)hu[1] << 16);
            pk.y = (uint32_t)hu[2] | ((uint32_t)hu[3] << 16);
            *(uint2*)&h2b[p ^ 1][rl][w * 16 + hi * 4] = pk;
        }

        // at chunk end, commit prefetched regs into the other xs buffer
        if ((t & 15) == 15 && (t + 1) < 1024 && tid < 256) {
            uint2 pk;
            pk.x = pk2f(xr0, xr1);
            pk.y = pk2f(xr2, 0.0f);
            *(uint2*)&xs[cb ^ 1][tt][sA][0] = pk;
        }
        __syncthreads();
        // hazards: reads from buf[p]/xs[cb], writes to buf[p^1]/xs[cb^1].
    }
    // final h2(1023) written at t=1024 (p=0) into h2b[1].

    // ---- decoder tail: wave wid handles samples {2wid, 2wid+1} ----
    #pragma unroll 1
    for (int ss = 0; ss < 2; ++ss) {
        const int s = wid * 2 + ss;
        const int S = blk * 16 + s;

        if (lane < 5) {   // u = enc_fc(h2_final)
            float acc = eb[lane];
            for (int k = 0; k < 64; ++k)
                acc += eW[lane * 64 + k] * (float)h2b[1][s][k];
            uW[wid][lane] = acc;
            out[S * 5 + lane] = acc;
        }
        __syncthreads();

        {   // d1: single step from zero state (only i, g, o gates matter)
            float u0 = uW[wid][0], u1 = uW[wid][1], u2 = uW[wid][2],
                  u3 = uW[wid][3], u4 = uW[wid][4];
            int ri = lane, rg = 128 + lane, ro = 192 + lane;
            float pi = D1bi[ri] + D1bh[ri];
            float pg = D1bi[rg] + D1bh[rg];
            float po = D1bi[ro] + D1bh[ro];
            pi += D1i[ri*5+0]*u0 + D1i[ri*5+1]*u1 + D1i[ri*5+2]*u2 + D1i[ri*5+3]*u3 + D1i[ri*5+4]*u4;
            pg += D1i[rg*5+0]*u0 + D1i[rg*5+1]*u1 + D1i[rg*5+2]*u2 + D1i[rg*5+3]*u3 + D1i[rg*5+4]*u4;
            po += D1i[ro*5+0]*u0 + D1i[ro*5+1]*u1 + D1i[ro*5+2]*u2 + D1i[ro*5+3]*u3 + D1i[ro*5+4]*u4;
            float cd = sigf(pi) * tanhf_fast(pg);
            float hd = sigf(po) * tanhf_fast(cd);
            tlA[wid][lane] = hd;
        }
        __syncthreads();

        {   // d2: single step from zero state
            int ri = lane, rg = 128 + lane, ro = 192 + lane;
            float pi = D2bi[ri] + D2bh[ri];
            float pg = D2bi[rg] + D2bh[rg];
            float po = D2bi[ro] + D2bh[ro];
            for (int k = 0; k < 64; ++k) {
                float hk = tlA[wid][k];
                pi += D2i[ri * 64 + k] * hk;
                pg += D2i[rg * 64 + k] * hk;
                po += D2i[ro * 64 + k] * hk;
            }
            float cd = sigf(pi) * tanhf_fast(pg);
            float hd = sigf(po) * tanhf_fast(cd);
            tlB[wid][lane] = hd;
        }
        __syncthreads();

        if (lane < 3) {   // tau = dec_fc(h_d2)
            float acc = db[lane];
            for (int k = 0; k < 64; ++k) acc += dW[lane * 64 + k] * tlB[wid][k];
            out[5120 + S * 3 + lane] = acc;
        }
        __syncthreads();
    }
}

extern "C" void kernel_launch(void* const* d_in, const int* in_sizes, int n_in,
                              void* d_out, int out_size, void* d_ws, size_t ws_size,
                              hipStream_t stream) {
    (void)in_sizes; (void)n_in; (void)out_size; (void)d_ws; (void)ws_size;
    const float* x    = (const float*)d_in[0];
    const float* W1i  = (const float*)d_in[1];
    const float* W1h  = (const float*)d_in[2];
    const float* b1i  = (const float*)d_in[3];
    const float* b1h  = (const float*)d_in[4];
    const float* W2i  = (const float*)d_in[5];
    const float* W2h  = (const float*)d_in[6];
    const float* b2i  = (const float*)d_in[7];
    const float* b2h  = (const float*)d_in[8];
    const float* eW   = (const float*)d_in[9];
    const float* eb   = (const float*)d_in[10];
    const float* D1i  = (const float*)d_in[11];
    const float* D1bi = (const float*)d_in[13];
    const float* D1bh = (const float*)d_in[14];
    const float* D2i  = (const float*)d_in[15];
    const float* D2bi = (const float*)d_in[17];
    const float* D2bh = (const float*)d_in[18];
    const float* dW   = (const float*)d_in[19];
    const float* db   = (const float*)d_in[20];

    hipLaunchKernelGGL(lstm_mfma16, dim3(64), dim3(512), 0, stream,
                       x, W1i, W1h, b1i, b1h, W2i, W2h, b2i, b2h, eW, eb,
                       D1i, D1bi, D1bh, D2i, D2bi, D2bh, dW, db,
                       (float*)d_out);
}